// Round 2
// baseline (1714.666 us; speedup 1.0000x reference)
//
#include <hip/hip_runtime.h>
#include <hip/hip_fp16.h>

#define NB 64
#define NN 512
#define DD 768

typedef _Float16 half8 __attribute__((ext_vector_type(8)));
typedef float f32x4 __attribute__((ext_vector_type(4)));

// order-preserving float<->int mapping (monotone for all floats incl. negatives)
__device__ __forceinline__ int f2ord(float f) {
  int i = __float_as_int(f);
  return i < 0 ? (i ^ 0x7fffffff) : i;
}
__device__ __forceinline__ float ord2f(int i) {
  return __int_as_float(i < 0 ? (i ^ 0x7fffffff) : i);
}

// ---------------- K0: init min/max meta ----------------
__global__ void k_init(int* meta) {
  if (threadIdx.x == 0) {
    meta[0] = 0x7fffffff;  // ordered-int +max (min accumulator)
    meta[1] = 0x80000000;  // ordered-int -max (max accumulator)
  }
}

// ---------------- K1: row-normalize + fp16 cast ----------------
// one wave per row; 65536 rows total (2 tensors x 64 x 512)
__global__ __launch_bounds__(256) void k_norm(const float* __restrict__ f1,
                                              const float* __restrict__ f2,
                                              __half* __restrict__ xn,
                                              __half* __restrict__ yn) {
  int row = blockIdx.x * 4 + (threadIdx.x >> 6);
  int lane = threadIdx.x & 63;
  int r = row & 32767;
  const float* src = (row < 32768 ? f1 : f2) + (size_t)r * DD;
  __half* dst = (row < 32768 ? xn : yn) + (size_t)r * DD;
  f32x4 v0 = *(const f32x4*)(src + lane * 4);
  f32x4 v1 = *(const f32x4*)(src + lane * 4 + 256);
  f32x4 v2 = *(const f32x4*)(src + lane * 4 + 512);
  float s = v0[0]*v0[0] + v0[1]*v0[1] + v0[2]*v0[2] + v0[3]*v0[3]
          + v1[0]*v1[0] + v1[1]*v1[1] + v1[2]*v1[2] + v1[3]*v1[3]
          + v2[0]*v2[0] + v2[1]*v2[1] + v2[2]*v2[2] + v2[3]*v2[3];
  #pragma unroll
  for (int m = 1; m < 64; m <<= 1) s += __shfl_xor(s, m, 64);
  float f = 1.0f / (sqrtf(s) + 1e-12f);
  union U { __half2 h2[2]; uint2 u; };
  U u0, u1, u2;
  u0.h2[0] = __floats2half2_rn(v0[0]*f, v0[1]*f); u0.h2[1] = __floats2half2_rn(v0[2]*f, v0[3]*f);
  u1.h2[0] = __floats2half2_rn(v1[0]*f, v1[1]*f); u1.h2[1] = __floats2half2_rn(v1[2]*f, v1[3]*f);
  u2.h2[0] = __floats2half2_rn(v2[0]*f, v2[1]*f); u2.h2[1] = __floats2half2_rn(v2[2]*f, v2[3]*f);
  *(uint2*)(dst + lane * 4)       = u0.u;
  *(uint2*)(dst + lane * 4 + 256) = u1.u;
  *(uint2*)(dst + lane * 4 + 512) = u2.u;
}

// ---------------- K2: batched fp16 MFMA GEMM: cos = 1 - xn @ yn^T ----------------
// grid (16, 64): blockIdx.x = 4x4 tile of 128x128, blockIdx.y = batch
__global__ void k_gemm(const __half* __restrict__ xn, const __half* __restrict__ yn,
                       float* __restrict__ cosm, int* __restrict__ meta) {
  __shared__ __align__(16) __half As[4096];  // [128][32]
  __shared__ __align__(16) __half Bs[4096];
  __shared__ float rmin[4], rmax[4];
  const int b  = blockIdx.y;
  const int ti = blockIdx.x >> 2;
  const int tj = blockIdx.x & 3;
  const int tid = threadIdx.x;
  const int wv = tid >> 6, lane = tid & 63;
  const int wr = (wv >> 1) * 64, wc = (wv & 1) * 64;
  const __half* Ab = xn + ((size_t)b * NN + (size_t)ti * 128) * DD;
  const __half* Bb = yn + ((size_t)b * NN + (size_t)tj * 128) * DD;
  const int srow = tid >> 2;
  const int scol = (tid & 3) * 8;
  const __half* ga0 = Ab + (size_t)srow * DD + scol;
  const __half* ga1 = ga0 + (size_t)64 * DD;
  const __half* gb0 = Bb + (size_t)srow * DD + scol;
  const __half* gb1 = gb0 + (size_t)64 * DD;
  __half* la0 = As + tid * 8;
  __half* la1 = As + 2048 + tid * 8;
  __half* lb0 = Bs + tid * 8;
  __half* lb1 = Bs + 2048 + tid * 8;
  f32x4 acc[4][4] = {};
  const int fr = lane & 15;
  const int kb = (lane >> 4) * 8;
  uint4 va0 = *(const uint4*)ga0;
  uint4 va1 = *(const uint4*)ga1;
  uint4 vb0 = *(const uint4*)gb0;
  uint4 vb1 = *(const uint4*)gb1;
  for (int kk = 0; kk < DD; kk += 32) {
    __syncthreads();
    *(uint4*)la0 = va0; *(uint4*)la1 = va1;
    *(uint4*)lb0 = vb0; *(uint4*)lb1 = vb1;
    __syncthreads();
    if (kk + 32 < DD) {  // prefetch next K-slab; overlaps MFMA below
      va0 = *(const uint4*)(ga0 + kk + 32);
      va1 = *(const uint4*)(ga1 + kk + 32);
      vb0 = *(const uint4*)(gb0 + kk + 32);
      vb1 = *(const uint4*)(gb1 + kk + 32);
    }
    half8 af[4], bf[4];
    #pragma unroll
    for (int g = 0; g < 4; ++g) {
      af[g] = *(const half8*)(As + (wr + g * 16 + fr) * 32 + kb);
      bf[g] = *(const half8*)(Bs + (wc + g * 16 + fr) * 32 + kb);
    }
    #pragma unroll
    for (int g = 0; g < 4; ++g) {
      #pragma unroll
      for (int h = 0; h < 4; ++h) {
        acc[g][h] = __builtin_amdgcn_mfma_f32_16x16x32_f16(af[g], bf[h], acc[g][h], 0, 0, 0);
      }
    }
  }
  float vmin = 1e30f, vmax = -1e30f;
  float* cb = cosm + (size_t)b * NN * NN;
  #pragma unroll
  for (int g = 0; g < 4; ++g) {
    #pragma unroll
    for (int h = 0; h < 4; ++h) {
      #pragma unroll
      for (int r2 = 0; r2 < 4; ++r2) {
        int row = ti * 128 + wr + g * 16 + (lane >> 4) * 4 + r2;
        int col = tj * 128 + wc + h * 16 + fr;
        float val = 1.0f - acc[g][h][r2];
        cb[(size_t)row * NN + col] = val;
        vmin = fminf(vmin, val); vmax = fmaxf(vmax, val);
      }
    }
  }
  #pragma unroll
  for (int m = 1; m < 64; m <<= 1) {
    vmin = fminf(vmin, __shfl_xor(vmin, m, 64));
    vmax = fmaxf(vmax, __shfl_xor(vmax, m, 64));
  }
  if (lane == 0) { rmin[wv] = vmin; rmax[wv] = vmax; }
  __syncthreads();
  if (tid == 0) {
    float bm = fminf(fminf(rmin[0], rmin[1]), fminf(rmin[2], rmin[3]));
    float bx = fmaxf(fmaxf(rmax[0], rmax[1]), fmaxf(rmax[2], rmax[3]));
    atomicMin(meta + 0, f2ord(bm));
    atomicMax(meta + 1, f2ord(bx));
  }
}

// ---------------- K4: 30 IPOT iterations, A and M=A^t resident in registers ----------------
// one block per batch; thread (ty,tx) owns 16x16 tile rows 16ty.., cols 16tx..
// NORMALIZED recursion (all per-iteration scalars cancel between x and y;
// exact identity: T_t = (1/m) * M ∘ x̂ ŷᵀ):
//   x̂_i = 1/(sum_j M_ij ẑ_j), ŷ_j = 1/(sum_i M_ij x̂_i), ẑ ← ŷ²/ŷ_prev, ẑ₁=1, ŷ₀=1
__global__ __launch_bounds__(1024, 1) void k_ipot(const float* __restrict__ cosm,
                                                  const int* __restrict__ meta,
                                                  float* __restrict__ dist) {
  __shared__ float xs[NN];
  __shared__ float ys[NN];
  __shared__ __half2 zpk[NN / 2];
  __shared__ __align__(16) __half2 csh[32][260];  // col-partials, fp16 pairs, padded
  __shared__ float wred[16];
  const int b = blockIdx.x;
  const int tid = threadIdx.x;
  const int ty = tid >> 5, tx = tid & 31;
  const int r0 = ty * 16, c0 = tx * 16;
  const float* cb = cosm + (size_t)b * NN * NN;
  const float gmn = ord2f(meta[0]);
  const float gmx = ord2f(meta[1]);
  const float thr = gmn + 0.1f * (gmx - gmn);

  __half2 Apk[128], Mpk[128];
  #pragma unroll
  for (int r = 0; r < 16; ++r) {
    const float* rp = cb + (size_t)(r0 + r) * NN + c0;
    #pragma unroll
    for (int q = 0; q < 4; ++q) {
      f32x4 v = *(const f32x4*)(rp + q * 4);
      float a0 = __expf(-2.0f * fmaxf(v[0] - thr, 0.0f));
      float a1 = __expf(-2.0f * fmaxf(v[1] - thr, 0.0f));
      float a2 = __expf(-2.0f * fmaxf(v[2] - thr, 0.0f));
      float a3 = __expf(-2.0f * fmaxf(v[3] - thr, 0.0f));
      Apk[r * 8 + q * 2]     = __floats2half2_rn(a0, a1);
      Apk[r * 8 + q * 2 + 1] = __floats2half2_rn(a2, a3);
    }
  }
  #pragma unroll
  for (int p = 0; p < 128; ++p) Mpk[p] = Apk[p];
  if (tid < 256) zpk[tid] = __floats2half2_rn(1.0f, 1.0f);  // ẑ₁ = 1
  if (tid < NN) ys[tid] = 1.0f;                             // ŷ₀ = 1
  __syncthreads();

  #pragma unroll 1
  for (int t = 1; t <= 30; ++t) {
    // ---- pass A: row sums r_i = sum_j M_ij ẑ_j; x̂_i = 1/r_i ----
    __half2 z2[8];
    #pragma unroll
    for (int q = 0; q < 8; ++q) z2[q] = zpk[tx * 8 + q];
    float rp16[16];
    #pragma unroll
    for (int r = 0; r < 16; ++r) {
      __half2 racc = __floats2half2_rn(0.0f, 0.0f);
      #pragma unroll
      for (int q = 0; q < 8; ++q) racc = __hfma2(Mpk[r * 8 + q], z2[q], racc);
      rp16[r] = __low2float(racc) + __high2float(racc);
    }
    // reduce-scatter 16 values over the 32 tx-lanes (static reg indexing only)
    float c8[8];
    #pragma unroll
    for (int i = 0; i < 8; ++i) {
      float keep = (tx & 1) ? rp16[2*i+1] : rp16[2*i];
      float send = (tx & 1) ? rp16[2*i]   : rp16[2*i+1];
      c8[i] = keep + __shfl_xor(send, 1, 64);
    }
    float c4[4];
    #pragma unroll
    for (int i = 0; i < 4; ++i) {
      float keep = (tx & 2) ? c8[2*i+1] : c8[2*i];
      float send = (tx & 2) ? c8[2*i]   : c8[2*i+1];
      c4[i] = keep + __shfl_xor(send, 2, 64);
    }
    float d2[2];
    #pragma unroll
    for (int i = 0; i < 2; ++i) {
      float keep = (tx & 4) ? c4[2*i+1] : c4[2*i];
      float send = (tx & 4) ? c4[2*i]   : c4[2*i+1];
      d2[i] = keep + __shfl_xor(send, 4, 64);
    }
    float c1;
    {
      float keep = (tx & 8) ? d2[1] : d2[0];
      float send = (tx & 8) ? d2[0] : d2[1];
      c1 = keep + __shfl_xor(send, 8, 64);
    }
    c1 += __shfl_xor(c1, 16, 64);
    if (tx < 16) xs[r0 + tx] = 1.0f / c1;  // lane tx holds total for row (tx&15)
    __syncthreads();
    // ---- pass B: col partials a_j = sum_i M_ij x̂_i ----
    __half2 cacc[8];
    #pragma unroll
    for (int q = 0; q < 8; ++q) cacc[q] = __floats2half2_rn(0.0f, 0.0f);
    #pragma unroll
    for (int r = 0; r < 16; ++r) {
      __half2 xh = __float2half2_rn(xs[r0 + r]);
      #pragma unroll
      for (int q = 0; q < 8; ++q) cacc[q] = __hfma2(Mpk[r * 8 + q], xh, cacc[q]);
    }
    #pragma unroll
    for (int q = 0; q < 8; ++q) csh[ty][tx * 8 + q] = cacc[q];
    if (t < 30) {  // M <- M * A  (pure-register, overlaps barrier latency)
      #pragma unroll
      for (int p = 0; p < 128; ++p) Mpk[p] = __hmul2(Mpk[p], Apk[p]);
    }
    __syncthreads();
    // ---- reduce cols, update ŷ, ẑ ----
    if (tid < 256) {
      float a0 = 0.0f, a1 = 0.0f;
      #pragma unroll
      for (int g = 0; g < 32; ++g) {
        float2 w = __half22float2(csh[g][tid]);
        a0 += w.x; a1 += w.y;
      }
      float yo0 = ys[2 * tid], yo1 = ys[2 * tid + 1];
      float y0 = 1.0f / a0;
      float y1 = 1.0f / a1;
      float z0 = y0 * y0 / yo0;
      float z1 = y1 * y1 / yo1;
      ys[2 * tid] = y0; ys[2 * tid + 1] = y1;
      zpk[tid] = __floats2half2_rn(z0, z1);
    }
    __syncthreads();
  }

  // ---- dist_b = sum_ij relu(C_ij - thr) * M_ij * x̂_i * ŷ_j   (M = A^30) ----
  // (true distance = dist_b / m; folded into k_final)
  float contrib = 0.0f;
  #pragma unroll
  for (int r = 0; r < 16; ++r) {
    const float* rp = cb + (size_t)(r0 + r) * NN + c0;
    float rowacc = 0.0f;
    #pragma unroll
    for (int q = 0; q < 4; ++q) {
      f32x4 v = *(const f32x4*)(rp + q * 4);
      float2 m0 = __half22float2(Mpk[r * 8 + q * 2]);
      float2 m1 = __half22float2(Mpk[r * 8 + q * 2 + 1]);
      rowacc += fmaxf(v[0] - thr, 0.0f) * m0.x * ys[c0 + q * 4 + 0];
      rowacc += fmaxf(v[1] - thr, 0.0f) * m0.y * ys[c0 + q * 4 + 1];
      rowacc += fmaxf(v[2] - thr, 0.0f) * m1.x * ys[c0 + q * 4 + 2];
      rowacc += fmaxf(v[3] - thr, 0.0f) * m1.y * ys[c0 + q * 4 + 3];
    }
    contrib += rowacc * xs[r0 + r];
  }
  #pragma unroll
  for (int m = 1; m < 64; m <<= 1) contrib += __shfl_xor(contrib, m, 64);
  if ((tid & 63) == 0) wred[tid >> 6] = contrib;
  __syncthreads();
  if (tid == 0) {
    float s2 = 0.0f;
    #pragma unroll
    for (int w2 = 0; w2 < 16; ++w2) s2 += wred[w2];
    dist[b] = s2;
  }
}

// ---------------- K5: deterministic finish: out = -mean_b(dist_b / m) ----------------
__global__ void k_final(const float* __restrict__ dist, float* __restrict__ out) {
  float v = dist[threadIdx.x & 63];
  #pragma unroll
  for (int m = 1; m < 64; m <<= 1) v += __shfl_xor(v, m, 64);
  if (threadIdx.x == 0) out[0] = -v * (1.0f / (64.0f * 512.0f));
}

extern "C" void kernel_launch(void* const* d_in, const int* in_sizes, int n_in,
                              void* d_out, int out_size, void* d_ws, size_t ws_size,
                              hipStream_t stream) {
  const float* f1 = (const float*)d_in[0];
  const float* f2 = (const float*)d_in[1];
  char* ws = (char*)d_ws;
  __half* xn  = (__half*)(ws + 0);                 // 50,331,648 B
  __half* yn  = (__half*)(ws + 50331648);          // 50,331,648 B
  float* cosm = (float*)(ws + 100663296);          // 67,108,864 B
  int*   meta = (int*)(ws + 167772160);            // 2 ints
  float* dist = (float*)(ws + 167772160 + 64);     // 64 floats

  k_init<<<1, 64, 0, stream>>>(meta);
  k_norm<<<16384, 256, 0, stream>>>(f1, f2, xn, yn);
  k_gemm<<<dim3(16, 64), 256, 0, stream>>>(xn, yn, cosm, meta);
  k_ipot<<<64, 1024, 0, stream>>>(cosm, meta, dist);
  k_final<<<1, 64, 0, stream>>>(dist, (float*)d_out);
}

// Round 3
// 649.050 us; speedup vs baseline: 2.6418x; 2.6418x over previous
//
#include <hip/hip_runtime.h>
#include <hip/hip_fp16.h>

#define NN 512
#define DD 768

typedef _Float16 half8 __attribute__((ext_vector_type(8)));
typedef float f32x4 __attribute__((ext_vector_type(4)));

// order-preserving float<->int mapping (monotone for all floats incl. negatives)
__device__ __forceinline__ int f2ord(float f) {
  int i = __float_as_int(f);
  return i < 0 ? (i ^ 0x7fffffff) : i;
}
__device__ __forceinline__ float ord2f(int i) {
  return __int_as_float(i < 0 ? (i ^ 0x7fffffff) : i);
}

// ---------------- K0: init min/max meta + per-batch barrier counters ----------------
__global__ void k_init(int* meta, int* cnt) {
  int t = threadIdx.x;
  if (t == 0) {
    meta[0] = 0x7fffffff;  // ordered-int +max (min accumulator)
    meta[1] = 0x80000000;  // ordered-int -max (max accumulator)
  }
  if (t < 64) cnt[t * 16] = 0;  // 64B-strided per-batch counters
}

// ---------------- K1: row-normalize + fp16 cast ----------------
__global__ __launch_bounds__(256) void k_norm(const float* __restrict__ f1,
                                              const float* __restrict__ f2,
                                              __half* __restrict__ xn,
                                              __half* __restrict__ yn) {
  int row = blockIdx.x * 4 + (threadIdx.x >> 6);
  int lane = threadIdx.x & 63;
  int r = row & 32767;
  const float* src = (row < 32768 ? f1 : f2) + (size_t)r * DD;
  __half* dst = (row < 32768 ? xn : yn) + (size_t)r * DD;
  f32x4 v0 = *(const f32x4*)(src + lane * 4);
  f32x4 v1 = *(const f32x4*)(src + lane * 4 + 256);
  f32x4 v2 = *(const f32x4*)(src + lane * 4 + 512);
  float s = v0[0]*v0[0] + v0[1]*v0[1] + v0[2]*v0[2] + v0[3]*v0[3]
          + v1[0]*v1[0] + v1[1]*v1[1] + v1[2]*v1[2] + v1[3]*v1[3]
          + v2[0]*v2[0] + v2[1]*v2[1] + v2[2]*v2[2] + v2[3]*v2[3];
  #pragma unroll
  for (int m = 1; m < 64; m <<= 1) s += __shfl_xor(s, m, 64);
  float f = 1.0f / (sqrtf(s) + 1e-12f);
  union U { __half2 h2[2]; uint2 u; };
  U u0, u1, u2;
  u0.h2[0] = __floats2half2_rn(v0[0]*f, v0[1]*f); u0.h2[1] = __floats2half2_rn(v0[2]*f, v0[3]*f);
  u1.h2[0] = __floats2half2_rn(v1[0]*f, v1[1]*f); u1.h2[1] = __floats2half2_rn(v1[2]*f, v1[3]*f);
  u2.h2[0] = __floats2half2_rn(v2[0]*f, v2[1]*f); u2.h2[1] = __floats2half2_rn(v2[2]*f, v2[3]*f);
  *(uint2*)(dst + lane * 4)       = u0.u;
  *(uint2*)(dst + lane * 4 + 256) = u1.u;
  *(uint2*)(dst + lane * 4 + 512) = u2.u;
}

// ---------------- K2: batched fp16 MFMA GEMM: cos = 1 - xn @ yn^T ----------------
__global__ void k_gemm(const __half* __restrict__ xn, const __half* __restrict__ yn,
                       float* __restrict__ cosm, int* __restrict__ meta) {
  __shared__ __align__(16) __half As[4096];  // [128][32]
  __shared__ __align__(16) __half Bs[4096];
  __shared__ float rmin[4], rmax[4];
  const int b  = blockIdx.y;
  const int ti = blockIdx.x >> 2;
  const int tj = blockIdx.x & 3;
  const int tid = threadIdx.x;
  const int wv = tid >> 6, lane = tid & 63;
  const int wr = (wv >> 1) * 64, wc = (wv & 1) * 64;
  const __half* Ab = xn + ((size_t)b * NN + (size_t)ti * 128) * DD;
  const __half* Bb = yn + ((size_t)b * NN + (size_t)tj * 128) * DD;
  const int srow = tid >> 2;
  const int scol = (tid & 3) * 8;
  const __half* ga0 = Ab + (size_t)srow * DD + scol;
  const __half* ga1 = ga0 + (size_t)64 * DD;
  const __half* gb0 = Bb + (size_t)srow * DD + scol;
  const __half* gb1 = gb0 + (size_t)64 * DD;
  __half* la0 = As + tid * 8;
  __half* la1 = As + 2048 + tid * 8;
  __half* lb0 = Bs + tid * 8;
  __half* lb1 = Bs + 2048 + tid * 8;
  f32x4 acc[4][4] = {};
  const int fr = lane & 15;
  const int kb = (lane >> 4) * 8;
  uint4 va0 = *(const uint4*)ga0;
  uint4 va1 = *(const uint4*)ga1;
  uint4 vb0 = *(const uint4*)gb0;
  uint4 vb1 = *(const uint4*)gb1;
  for (int kk = 0; kk < DD; kk += 32) {
    __syncthreads();
    *(uint4*)la0 = va0; *(uint4*)la1 = va1;
    *(uint4*)lb0 = vb0; *(uint4*)lb1 = vb1;
    __syncthreads();
    if (kk + 32 < DD) {
      va0 = *(const uint4*)(ga0 + kk + 32);
      va1 = *(const uint4*)(ga1 + kk + 32);
      vb0 = *(const uint4*)(gb0 + kk + 32);
      vb1 = *(const uint4*)(gb1 + kk + 32);
    }
    half8 af[4], bf[4];
    #pragma unroll
    for (int g = 0; g < 4; ++g) {
      af[g] = *(const half8*)(As + (wr + g * 16 + fr) * 32 + kb);
      bf[g] = *(const half8*)(Bs + (wc + g * 16 + fr) * 32 + kb);
    }
    #pragma unroll
    for (int g = 0; g < 4; ++g) {
      #pragma unroll
      for (int h = 0; h < 4; ++h) {
        acc[g][h] = __builtin_amdgcn_mfma_f32_16x16x32_f16(af[g], bf[h], acc[g][h], 0, 0, 0);
      }
    }
  }
  float vmin = 1e30f, vmax = -1e30f;
  float* cb = cosm + (size_t)b * NN * NN;
  #pragma unroll
  for (int g = 0; g < 4; ++g) {
    #pragma unroll
    for (int h = 0; h < 4; ++h) {
      #pragma unroll
      for (int r2 = 0; r2 < 4; ++r2) {
        int row = ti * 128 + wr + g * 16 + (lane >> 4) * 4 + r2;
        int col = tj * 128 + wc + h * 16 + fr;
        float val = 1.0f - acc[g][h][r2];
        cb[(size_t)row * NN + col] = val;
        vmin = fminf(vmin, val); vmax = fmaxf(vmax, val);
      }
    }
  }
  #pragma unroll
  for (int m = 1; m < 64; m <<= 1) {
    vmin = fminf(vmin, __shfl_xor(vmin, m, 64));
    vmax = fmaxf(vmax, __shfl_xor(vmax, m, 64));
  }
  if (lane == 0) { rmin[wv] = vmin; rmax[wv] = vmax; }
  __syncthreads();
  if (tid == 0) {
    float bm = fminf(fminf(rmin[0], rmin[1]), fminf(rmin[2], rmin[3]));
    float bx = fmaxf(fmaxf(rmax[0], rmax[1]), fmaxf(rmax[2], rmax[3]));
    atomicMin(meta + 0, f2ord(bm));
    atomicMax(meta + 1, f2ord(bx));
  }
}

// ---------------- K3: 30 IPOT iterations, 4 blocks per batch, A/M in registers ----------------
// block (b, qq) owns rows [qq*128, qq*128+128) of batch b. 512 threads:
// wave w (0..7) owns rows r0=w*16..+16; lane owns cols c0=lane*8..+8.
// State/thread: A2[64]+M2[64] __half2 = 128 VGPR. Normalized recursion (exact:
// T_t = (1/m) M ∘ x̂ŷᵀ): x̂=1/(Mẑ), ŷ=1/(Mᵀx̂), ẑ←ŷ²/ŷ_prev, ẑ₁=1, ŷ₀=1.
// Cross-block col-sum reduction: double-buffered fp32 partials in gpart +
// per-batch monotonic counter barrier (release add / acquire spin).
__global__ __launch_bounds__(512, 2) void k_ipot(const float* __restrict__ cosm,
                                                 const int* __restrict__ meta,
                                                 int* __restrict__ cnt,
                                                 float* __restrict__ gpart,
                                                 float* __restrict__ gdist) {
  __shared__ float xs[128];
  __shared__ float ys[NN];
  __shared__ __half2 zpk[NN / 2];
  __shared__ __half2 csh[8][260];
  __shared__ float wred[8];
  const int blk = blockIdx.x;
  const int b = blk >> 2, qq = blk & 3;
  const int tid = threadIdx.x;
  const int w = tid >> 6, lane = tid & 63;
  const int r0 = w * 16;
  const int c0 = lane * 8;
  const float* cb = cosm + (size_t)b * NN * NN + (size_t)(qq * 128) * NN;
  const float gmn = ord2f(meta[0]);
  const float gmx = ord2f(meta[1]);
  const float thr = gmn + 0.1f * (gmx - gmn);

  __half2 A2[64], M2[64];
  #pragma unroll
  for (int r = 0; r < 16; ++r) {
    const float* rp = cb + (size_t)(r0 + r) * NN + c0;
    f32x4 v0 = *(const f32x4*)rp;
    f32x4 v1 = *(const f32x4*)(rp + 4);
    float a0 = __expf(-2.0f * fmaxf(v0[0] - thr, 0.0f));
    float a1 = __expf(-2.0f * fmaxf(v0[1] - thr, 0.0f));
    float a2 = __expf(-2.0f * fmaxf(v0[2] - thr, 0.0f));
    float a3 = __expf(-2.0f * fmaxf(v0[3] - thr, 0.0f));
    float a4 = __expf(-2.0f * fmaxf(v1[0] - thr, 0.0f));
    float a5 = __expf(-2.0f * fmaxf(v1[1] - thr, 0.0f));
    float a6 = __expf(-2.0f * fmaxf(v1[2] - thr, 0.0f));
    float a7 = __expf(-2.0f * fmaxf(v1[3] - thr, 0.0f));
    A2[r * 4 + 0] = __floats2half2_rn(a0, a1);
    A2[r * 4 + 1] = __floats2half2_rn(a2, a3);
    A2[r * 4 + 2] = __floats2half2_rn(a4, a5);
    A2[r * 4 + 3] = __floats2half2_rn(a6, a7);
  }
  #pragma unroll
  for (int p = 0; p < 64; ++p) M2[p] = A2[p];
  if (tid < 256) zpk[tid] = __floats2half2_rn(1.0f, 1.0f);  // ẑ₁ = 1
  ys[tid] = 1.0f;                                           // ŷ₀ = 1 (512 threads)
  __syncthreads();

  int* mycnt = cnt + b * 16;

  #pragma unroll 1
  for (int t = 1; t <= 30; ++t) {
    // ---- row pass: r_i = sum_j M_ij ẑ_j over own 8 cols; x̂ = 1/rowsum ----
    __half2 z2[4];
    #pragma unroll
    for (int q = 0; q < 4; ++q) z2[q] = zpk[lane * 4 + q];
    float rp16[16];
    #pragma unroll
    for (int r = 0; r < 16; ++r) {
      __half2 racc = __floats2half2_rn(0.0f, 0.0f);
      #pragma unroll
      for (int q = 0; q < 4; ++q) racc = __hfma2(M2[r * 4 + q], z2[q], racc);
      rp16[r] = __low2float(racc) + __high2float(racc);
    }
    // reduce-scatter 16 row-partials over 64 lanes (static reg indexing only)
    float c8[8];
    #pragma unroll
    for (int i = 0; i < 8; ++i) {
      float keep = (lane & 1) ? rp16[2*i+1] : rp16[2*i];
      float send = (lane & 1) ? rp16[2*i]   : rp16[2*i+1];
      c8[i] = keep + __shfl_xor(send, 1, 64);
    }
    float c4[4];
    #pragma unroll
    for (int i = 0; i < 4; ++i) {
      float keep = (lane & 2) ? c8[2*i+1] : c8[2*i];
      float send = (lane & 2) ? c8[2*i]   : c8[2*i+1];
      c4[i] = keep + __shfl_xor(send, 2, 64);
    }
    float d2[2];
    #pragma unroll
    for (int i = 0; i < 2; ++i) {
      float keep = (lane & 4) ? c4[2*i+1] : c4[2*i];
      float send = (lane & 4) ? c4[2*i]   : c4[2*i+1];
      d2[i] = keep + __shfl_xor(send, 4, 64);
    }
    float c1;
    {
      float keep = (lane & 8) ? d2[1] : d2[0];
      float send = (lane & 8) ? d2[0] : d2[1];
      c1 = keep + __shfl_xor(send, 8, 64);
    }
    c1 += __shfl_xor(c1, 16, 64);
    c1 += __shfl_xor(c1, 32, 64);
    if (lane < 16) xs[r0 + lane] = 1.0f / c1;  // lane holds rowsum of row (lane&15)
    __syncthreads();
    // ---- col pass: partial a_j over own 16 rows ----
    __half2 cacc[4];
    #pragma unroll
    for (int q = 0; q < 4; ++q) cacc[q] = __floats2half2_rn(0.0f, 0.0f);
    #pragma unroll
    for (int r = 0; r < 16; ++r) {
      __half2 xh = __float2half2_rn(xs[r0 + r]);
      #pragma unroll
      for (int q = 0; q < 4; ++q) cacc[q] = __hfma2(M2[r * 4 + q], xh, cacc[q]);
    }
    #pragma unroll
    for (int q = 0; q < 4; ++q) csh[w][lane * 4 + q] = cacc[q];
    if (t < 30) {  // M <- M*A in regs, overlaps LDS latency
      #pragma unroll
      for (int p = 0; p < 64; ++p) M2[p] = __hmul2(M2[p], A2[p]);
    }
    __syncthreads();
    // ---- block-local col reduce -> global partial ----
    float* gp = gpart + ((size_t)((t & 1) * 256 + blk) * 256) * 2;
    if (tid < 256) {
      float a0 = 0.0f, a1 = 0.0f;
      #pragma unroll
      for (int g = 0; g < 8; ++g) {
        float2 wv = __half22float2(csh[g][tid]);
        a0 += wv.x; a1 += wv.y;
      }
      gp[tid * 2] = a0; gp[tid * 2 + 1] = a1;
    }
    __syncthreads();  // drains vmcnt: all partial stores issued & complete
    // ---- 4-block barrier (per-batch monotonic counter) ----
    if (tid == 0) {
      __threadfence();  // device-scope visibility of partials
      __hip_atomic_fetch_add(mycnt, 1, __ATOMIC_ACQ_REL, __HIP_MEMORY_SCOPE_AGENT);
      while (__hip_atomic_load(mycnt, __ATOMIC_ACQUIRE, __HIP_MEMORY_SCOPE_AGENT) < 4 * t)
        __builtin_amdgcn_s_sleep(2);
    }
    __syncthreads();
    // ---- read all 4 quarters' partials, replicated y/z update ----
    if (tid < 256) {
      float* gpb = gpart + ((size_t)((t & 1) * 256 + b * 4) * 256) * 2;
      float a0 = 0.0f, a1 = 0.0f;
      #pragma unroll
      for (int q2 = 0; q2 < 4; ++q2) {  // agent-scope loads (bypass stale L1)
        a0 += __hip_atomic_load(gpb + q2 * 512 + tid * 2,     __ATOMIC_RELAXED, __HIP_MEMORY_SCOPE_AGENT);
        a1 += __hip_atomic_load(gpb + q2 * 512 + tid * 2 + 1, __ATOMIC_RELAXED, __HIP_MEMORY_SCOPE_AGENT);
      }
      float yo0 = ys[2 * tid], yo1 = ys[2 * tid + 1];
      float y0 = 1.0f / a0;
      float y1 = 1.0f / a1;
      zpk[tid] = __floats2half2_rn(y0 * y0 / yo0, y1 * y1 / yo1);
      ys[2 * tid] = y0; ys[2 * tid + 1] = y1;
    }
    __syncthreads();
  }

  // ---- dist partial = sum_ij relu(C-thr) * M_ij * x̂_i * ŷ_j over own patch ----
  float contrib = 0.0f;
  #pragma unroll
  for (int r = 0; r < 16; ++r) {
    const float* rp = cb + (size_t)(r0 + r) * NN + c0;
    f32x4 v0 = *(const f32x4*)rp;
    f32x4 v1 = *(const f32x4*)(rp + 4);
    float2 m0 = __half22float2(M2[r * 4 + 0]);
    float2 m1 = __half22float2(M2[r * 4 + 1]);
    float2 m2 = __half22float2(M2[r * 4 + 2]);
    float2 m3 = __half22float2(M2[r * 4 + 3]);
    float rowacc = 0.0f;
    rowacc += fmaxf(v0[0] - thr, 0.0f) * m0.x * ys[c0 + 0];
    rowacc += fmaxf(v0[1] - thr, 0.0f) * m0.y * ys[c0 + 1];
    rowacc += fmaxf(v0[2] - thr, 0.0f) * m1.x * ys[c0 + 2];
    rowacc += fmaxf(v0[3] - thr, 0.0f) * m1.y * ys[c0 + 3];
    rowacc += fmaxf(v1[0] - thr, 0.0f) * m2.x * ys[c0 + 4];
    rowacc += fmaxf(v1[1] - thr, 0.0f) * m2.y * ys[c0 + 5];
    rowacc += fmaxf(v1[2] - thr, 0.0f) * m3.x * ys[c0 + 6];
    rowacc += fmaxf(v1[3] - thr, 0.0f) * m3.y * ys[c0 + 7];
    contrib += rowacc * xs[r0 + r];
  }
  #pragma unroll
  for (int m = 1; m < 64; m <<= 1) contrib += __shfl_xor(contrib, m, 64);
  if (lane == 0) wred[w] = contrib;
  __syncthreads();
  if (tid == 0) {
    float s2 = 0.0f;
    #pragma unroll
    for (int g = 0; g < 8; ++g) s2 += wred[g];
    gdist[blk] = s2;
  }
}

// ---------------- K5: deterministic finish: out = -mean_b(dist_b / m) ----------------
__global__ void k_final(const float* __restrict__ gdist, float* __restrict__ out) {
  int b = threadIdx.x & 63;
  float v = gdist[b * 4] + gdist[b * 4 + 1] + gdist[b * 4 + 2] + gdist[b * 4 + 3];
  #pragma unroll
  for (int m = 1; m < 64; m <<= 1) v += __shfl_xor(v, m, 64);
  if (threadIdx.x == 0) out[0] = -v * (1.0f / (64.0f * 512.0f));
}

extern "C" void kernel_launch(void* const* d_in, const int* in_sizes, int n_in,
                              void* d_out, int out_size, void* d_ws, size_t ws_size,
                              hipStream_t stream) {
  const float* f1 = (const float*)d_in[0];
  const float* f2 = (const float*)d_in[1];
  char* ws = (char*)d_ws;
  __half* xn  = (__half*)(ws + 0);                 // 50,331,648 B
  __half* yn  = (__half*)(ws + 50331648);          // 50,331,648 B (dead after k_gemm)
  float* gpart = (float*)(ws + 50331648);          // 1 MB, overlaps yn (used only in k_ipot)
  float* cosm = (float*)(ws + 100663296);          // 67,108,864 B
  int*   meta = (int*)(ws + 167772160);            // 2 ints
  int*   cnt  = (int*)(ws + 167772160 + 256);      // 64 x 16 ints (4 KB)
  float* gdist = (float*)(ws + 167772160 + 256 + 4096);  // 256 floats

  k_init<<<1, 64, 0, stream>>>(meta, cnt);
  k_norm<<<16384, 256, 0, stream>>>(f1, f2, xn, yn);
  k_gemm<<<dim3(16, 64), 256, 0, stream>>>(xn, yn, cosm, meta);
  k_ipot<<<256, 512, 0, stream>>>(cosm, meta, cnt, gpart, gdist);
  k_final<<<1, 64, 0, stream>>>(gdist, (float*)d_out);
}

// Round 4
// 514.882 us; speedup vs baseline: 3.3302x; 1.2606x over previous
//
#include <hip/hip_runtime.h>
#include <hip/hip_fp16.h>

#define NN 512
#define DD 768

typedef _Float16 half8 __attribute__((ext_vector_type(8)));
typedef _Float16 half4 __attribute__((ext_vector_type(4)));
typedef _Float16 half2v __attribute__((ext_vector_type(2)));
typedef float f32x4 __attribute__((ext_vector_type(4)));

// order-preserving float<->int mapping (monotone for all floats incl. negatives)
__device__ __forceinline__ int f2ord(float f) {
  int i = __float_as_int(f);
  return i < 0 ? (i ^ 0x7fffffff) : i;
}
__device__ __forceinline__ float ord2f(int i) {
  return __int_as_float(i < 0 ? (i ^ 0x7fffffff) : i);
}

// ---------------- K0: init min/max meta + per-batch barrier counters ----------------
__global__ void k_init(int* meta, int* cnt) {
  int t = threadIdx.x;
  if (t == 0) {
    meta[0] = 0x7fffffff;  // ordered-int +max (min accumulator)
    meta[1] = 0x80000000;  // ordered-int -max (max accumulator)
  }
  if (t < 64) cnt[t * 16] = 0;  // 64B-strided per-batch counters
}

// ---------------- K1: row-normalize + fp16 cast ----------------
__global__ __launch_bounds__(256) void k_norm(const float* __restrict__ f1,
                                              const float* __restrict__ f2,
                                              __half* __restrict__ xn,
                                              __half* __restrict__ yn) {
  int row = blockIdx.x * 4 + (threadIdx.x >> 6);
  int lane = threadIdx.x & 63;
  int r = row & 32767;
  const float* src = (row < 32768 ? f1 : f2) + (size_t)r * DD;
  __half* dst = (row < 32768 ? xn : yn) + (size_t)r * DD;
  f32x4 v0 = *(const f32x4*)(src + lane * 4);
  f32x4 v1 = *(const f32x4*)(src + lane * 4 + 256);
  f32x4 v2 = *(const f32x4*)(src + lane * 4 + 512);
  float s = v0[0]*v0[0] + v0[1]*v0[1] + v0[2]*v0[2] + v0[3]*v0[3]
          + v1[0]*v1[0] + v1[1]*v1[1] + v1[2]*v1[2] + v1[3]*v1[3]
          + v2[0]*v2[0] + v2[1]*v2[1] + v2[2]*v2[2] + v2[3]*v2[3];
  #pragma unroll
  for (int m = 1; m < 64; m <<= 1) s += __shfl_xor(s, m, 64);
  float f = 1.0f / (sqrtf(s) + 1e-12f);
  union U { __half2 h2[2]; uint2 u; };
  U u0, u1, u2;
  u0.h2[0] = __floats2half2_rn(v0[0]*f, v0[1]*f); u0.h2[1] = __floats2half2_rn(v0[2]*f, v0[3]*f);
  u1.h2[0] = __floats2half2_rn(v1[0]*f, v1[1]*f); u1.h2[1] = __floats2half2_rn(v1[2]*f, v1[3]*f);
  u2.h2[0] = __floats2half2_rn(v2[0]*f, v2[1]*f); u2.h2[1] = __floats2half2_rn(v2[2]*f, v2[3]*f);
  *(uint2*)(dst + lane * 4)       = u0.u;
  *(uint2*)(dst + lane * 4 + 256) = u1.u;
  *(uint2*)(dst + lane * 4 + 512) = u2.u;
}

// ---------------- K2: batched fp16 MFMA GEMM: cos = 1 - xn @ yn^T ----------------
__global__ void k_gemm(const __half* __restrict__ xn, const __half* __restrict__ yn,
                       float* __restrict__ cosm, int* __restrict__ meta) {
  __shared__ __align__(16) __half As[4096];  // [128][32]
  __shared__ __align__(16) __half Bs[4096];
  __shared__ float rmin[4], rmax[4];
  const int b  = blockIdx.y;
  const int ti = blockIdx.x >> 2;
  const int tj = blockIdx.x & 3;
  const int tid = threadIdx.x;
  const int wv = tid >> 6, lane = tid & 63;
  const int wr = (wv >> 1) * 64, wc = (wv & 1) * 64;
  const __half* Ab = xn + ((size_t)b * NN + (size_t)ti * 128) * DD;
  const __half* Bb = yn + ((size_t)b * NN + (size_t)tj * 128) * DD;
  const int srow = tid >> 2;
  const int scol = (tid & 3) * 8;
  const __half* ga0 = Ab + (size_t)srow * DD + scol;
  const __half* ga1 = ga0 + (size_t)64 * DD;
  const __half* gb0 = Bb + (size_t)srow * DD + scol;
  const __half* gb1 = gb0 + (size_t)64 * DD;
  __half* la0 = As + tid * 8;
  __half* la1 = As + 2048 + tid * 8;
  __half* lb0 = Bs + tid * 8;
  __half* lb1 = Bs + 2048 + tid * 8;
  f32x4 acc[4][4] = {};
  const int fr = lane & 15;
  const int kb = (lane >> 4) * 8;
  typedef _Float16 mhalf8 __attribute__((ext_vector_type(8)));
  uint4 va0 = *(const uint4*)ga0;
  uint4 va1 = *(const uint4*)ga1;
  uint4 vb0 = *(const uint4*)gb0;
  uint4 vb1 = *(const uint4*)gb1;
  for (int kk = 0; kk < DD; kk += 32) {
    __syncthreads();
    *(uint4*)la0 = va0; *(uint4*)la1 = va1;
    *(uint4*)lb0 = vb0; *(uint4*)lb1 = vb1;
    __syncthreads();
    if (kk + 32 < DD) {
      va0 = *(const uint4*)(ga0 + kk + 32);
      va1 = *(const uint4*)(ga1 + kk + 32);
      vb0 = *(const uint4*)(gb0 + kk + 32);
      vb1 = *(const uint4*)(gb1 + kk + 32);
    }
    mhalf8 af[4], bf[4];
    #pragma unroll
    for (int g = 0; g < 4; ++g) {
      af[g] = *(const mhalf8*)(As + (wr + g * 16 + fr) * 32 + kb);
      bf[g] = *(const mhalf8*)(Bs + (wc + g * 16 + fr) * 32 + kb);
    }
    #pragma unroll
    for (int g = 0; g < 4; ++g) {
      #pragma unroll
      for (int h = 0; h < 4; ++h) {
        acc[g][h] = __builtin_amdgcn_mfma_f32_16x16x32_f16(af[g], bf[h], acc[g][h], 0, 0, 0);
      }
    }
  }
  float vmin = 1e30f, vmax = -1e30f;
  float* cb = cosm + (size_t)b * NN * NN;
  #pragma unroll
  for (int g = 0; g < 4; ++g) {
    #pragma unroll
    for (int h = 0; h < 4; ++h) {
      #pragma unroll
      for (int r2 = 0; r2 < 4; ++r2) {
        int row = ti * 128 + wr + g * 16 + (lane >> 4) * 4 + r2;
        int col = tj * 128 + wc + h * 16 + fr;
        float val = 1.0f - acc[g][h][r2];
        cb[(size_t)row * NN + col] = val;
        vmin = fminf(vmin, val); vmax = fmaxf(vmax, val);
      }
    }
  }
  #pragma unroll
  for (int m = 1; m < 64; m <<= 1) {
    vmin = fminf(vmin, __shfl_xor(vmin, m, 64));
    vmax = fmaxf(vmax, __shfl_xor(vmax, m, 64));
  }
  if (lane == 0) { rmin[wv] = vmin; rmax[wv] = vmax; }
  __syncthreads();
  if (tid == 0) {
    float bm = fminf(fminf(rmin[0], rmin[1]), fminf(rmin[2], rmin[3]));
    float bx = fmaxf(fmaxf(rmax[0], rmax[1]), fmaxf(rmax[2], rmax[3]));
    atomicMin(meta + 0, f2ord(bm));
    atomicMax(meta + 1, f2ord(bx));
  }
}

// ---------------- K3: 30 IPOT iterations, 4 blocks/batch, A/M in NAMED half8 registers ----
// blk -> batch b = blk&63, quarter qq = blk>>6 (the 4 partner blocks share an XCD).
// Block owns rows [qq*128, +128); wave w owns 16 rows; lane owns 8 cols (c0=lane*8).
// Per-thread state: 16x half8 A + 16x half8 M = 128 VGPR, all NAMED variables
// (no arrays -> no SROA failure -> no scratch; round-3 fix for VGPR_Count=88 spill).
// Normalized recursion (exact: T_t = (1/m) M ∘ x̂ŷᵀ):
//   x̂=1/(Mẑ), ŷ=1/(Mᵀx̂), ẑ←ŷ²/ŷ_prev, ẑ₁=1, ŷ₀=1
#define FOR16(X) X(0) X(1) X(2) X(3) X(4) X(5) X(6) X(7) X(8) X(9) X(10) X(11) X(12) X(13) X(14) X(15)

__global__ __launch_bounds__(512, 2) void k_ipot(const float* __restrict__ cosm,
                                                 const int* __restrict__ meta,
                                                 int* __restrict__ cnt,
                                                 float* __restrict__ gpart,
                                                 float* __restrict__ gdist) {
  __shared__ float xs[128];
  __shared__ float ys[NN];
  __shared__ __align__(16) _Float16 zs[NN];
  __shared__ __align__(16) _Float16 csh[8][520];  // 8 waves x 512 cols (+8 pad)
  __shared__ float wred[8];
  const int blk = blockIdx.x;
  const int b = blk & 63, qq = blk >> 6;
  const int tid = threadIdx.x;
  const int w = tid >> 6, lane = tid & 63;
  const int r0 = w * 16;
  const int c0 = lane * 8;
  const float* cb = cosm + (size_t)b * NN * NN + (size_t)(qq * 128) * NN;
  const float gmn = ord2f(meta[0]);
  const float gmx = ord2f(meta[1]);
  const float thr = gmn + 0.1f * (gmx - gmn);

#define DECLAM(r) half8 A##r, M##r;
  FOR16(DECLAM)

#define INITAM(r) { \
    const float* rp = cb + (size_t)(r0 + r) * NN + c0; \
    f32x4 v0 = *(const f32x4*)rp; \
    f32x4 v1 = *(const f32x4*)(rp + 4); \
    A##r.s0 = (_Float16)__expf(-2.0f * fmaxf(v0[0] - thr, 0.0f)); \
    A##r.s1 = (_Float16)__expf(-2.0f * fmaxf(v0[1] - thr, 0.0f)); \
    A##r.s2 = (_Float16)__expf(-2.0f * fmaxf(v0[2] - thr, 0.0f)); \
    A##r.s3 = (_Float16)__expf(-2.0f * fmaxf(v0[3] - thr, 0.0f)); \
    A##r.s4 = (_Float16)__expf(-2.0f * fmaxf(v1[0] - thr, 0.0f)); \
    A##r.s5 = (_Float16)__expf(-2.0f * fmaxf(v1[1] - thr, 0.0f)); \
    A##r.s6 = (_Float16)__expf(-2.0f * fmaxf(v1[2] - thr, 0.0f)); \
    A##r.s7 = (_Float16)__expf(-2.0f * fmaxf(v1[3] - thr, 0.0f)); \
    M##r = A##r; }
  FOR16(INITAM)

  if (tid < 256) *(half2v*)(zs + 2 * tid) = (half2v){(_Float16)1.0f, (_Float16)1.0f};  // ẑ₁=1
  ys[tid] = 1.0f;  // ŷ₀=1 (512 threads cover 512 cols)
  __syncthreads();

  int* mycnt = cnt + b * 16;

  #pragma unroll 1
  for (int t = 1; t <= 30; ++t) {
    // ---- row pass: per-row partial = sum over own 8 cols of M*ẑ ----
    half8 zv = *(const half8*)(zs + c0);
    float rp16[16];
#define ROWP(r) { \
      half8 p = M##r * zv; \
      half4 q = p.lo + p.hi; \
      half2v q2 = q.lo + q.hi; \
      rp16[r] = (float)q2.x + (float)q2.y; }
    FOR16(ROWP)
    // reduce-scatter 16 row-partials over 64 lanes (static indices only)
    float c8[8];
    #pragma unroll
    for (int i = 0; i < 8; ++i) {
      float keep = (lane & 1) ? rp16[2*i+1] : rp16[2*i];
      float send = (lane & 1) ? rp16[2*i]   : rp16[2*i+1];
      c8[i] = keep + __shfl_xor(send, 1, 64);
    }
    float c4[4];
    #pragma unroll
    for (int i = 0; i < 4; ++i) {
      float keep = (lane & 2) ? c8[2*i+1] : c8[2*i];
      float send = (lane & 2) ? c8[2*i]   : c8[2*i+1];
      c4[i] = keep + __shfl_xor(send, 2, 64);
    }
    float d2[2];
    #pragma unroll
    for (int i = 0; i < 2; ++i) {
      float keep = (lane & 4) ? c4[2*i+1] : c4[2*i];
      float send = (lane & 4) ? c4[2*i]   : c4[2*i+1];
      d2[i] = keep + __shfl_xor(send, 4, 64);
    }
    float c1;
    {
      float keep = (lane & 8) ? d2[1] : d2[0];
      float send = (lane & 8) ? d2[0] : d2[1];
      c1 = keep + __shfl_xor(send, 8, 64);
    }
    c1 += __shfl_xor(c1, 16, 64);
    c1 += __shfl_xor(c1, 32, 64);
    if (lane < 16) xs[r0 + lane] = 1.0f / c1;  // x̂ for row (lane&15) of this wave
    __syncthreads();
    // ---- col pass: cac_j = sum over own 16 rows of M*x̂ ----
    half8 cac = (half8)(_Float16)0.0f;
#define COLP(r) { _Float16 xh = (_Float16)xs[r0 + r]; cac += M##r * xh; }
    FOR16(COLP)
    *(half8*)(&csh[w][c0]) = cac;
#define UPDM(r) M##r *= A##r;
    if (t < 30) { FOR16(UPDM) }  // M <- M∘A in regs, overlaps LDS latency
    __syncthreads();
    // ---- block-local col reduce -> global fp32 partial (double-buffered) ----
    float* gp = gpart + ((size_t)((t & 1) * 256 + blk) * 512);
    if (tid < 256) {
      float a0 = 0.0f, a1 = 0.0f;
      #pragma unroll
      for (int g = 0; g < 8; ++g) {
        half2v pv = *(const half2v*)(&csh[g][2 * tid]);
        a0 += (float)pv.x; a1 += (float)pv.y;
      }
      gp[tid * 2] = a0; gp[tid * 2 + 1] = a1;
    }
    __syncthreads();  // all partial stores drained (vmcnt 0 at barrier)
    // ---- 4-block barrier (per-batch monotonic counter) ----
    if (tid == 0) {
      __threadfence();
      __hip_atomic_fetch_add(mycnt, 1, __ATOMIC_ACQ_REL, __HIP_MEMORY_SCOPE_AGENT);
      while (__hip_atomic_load(mycnt, __ATOMIC_ACQUIRE, __HIP_MEMORY_SCOPE_AGENT) < 4 * t)
        __builtin_amdgcn_s_sleep(2);
    }
    __syncthreads();
    // ---- read 4 partners' partials (blk = b + 64*q2), replicated ŷ/ẑ update ----
    if (tid < 256) {
      float a0 = 0.0f, a1 = 0.0f;
      #pragma unroll
      for (int q2 = 0; q2 < 4; ++q2) {
        const float* gpb = gpart + ((size_t)((t & 1) * 256 + b + 64 * q2) * 512);
        a0 += __hip_atomic_load(gpb + tid * 2,     __ATOMIC_RELAXED, __HIP_MEMORY_SCOPE_AGENT);
        a1 += __hip_atomic_load(gpb + tid * 2 + 1, __ATOMIC_RELAXED, __HIP_MEMORY_SCOPE_AGENT);
      }
      float yo0 = ys[2 * tid], yo1 = ys[2 * tid + 1];
      float y0 = 1.0f / a0;
      float y1 = 1.0f / a1;
      *(half2v*)(zs + 2 * tid) = (half2v){(_Float16)(y0 * y0 / yo0), (_Float16)(y1 * y1 / yo1)};
      ys[2 * tid] = y0; ys[2 * tid + 1] = y1;
    }
    __syncthreads();
  }

  // ---- dist partial = sum_ij relu(C-thr) * M_ij * x̂_i * ŷ_j over own patch ----
  float contrib = 0.0f;
#define FINP(r) { \
    const float* rp = cb + (size_t)(r0 + r) * NN + c0; \
    f32x4 v0 = *(const f32x4*)rp; \
    f32x4 v1 = *(const f32x4*)(rp + 4); \
    float rowacc = 0.0f; \
    rowacc += fmaxf(v0[0] - thr, 0.0f) * (float)M##r.s0 * ys[c0 + 0]; \
    rowacc += fmaxf(v0[1] - thr, 0.0f) * (float)M##r.s1 * ys[c0 + 1]; \
    rowacc += fmaxf(v0[2] - thr, 0.0f) * (float)M##r.s2 * ys[c0 + 2]; \
    rowacc += fmaxf(v0[3] - thr, 0.0f) * (float)M##r.s3 * ys[c0 + 3]; \
    rowacc += fmaxf(v1[0] - thr, 0.0f) * (float)M##r.s4 * ys[c0 + 4]; \
    rowacc += fmaxf(v1[1] - thr, 0.0f) * (float)M##r.s5 * ys[c0 + 5]; \
    rowacc += fmaxf(v1[2] - thr, 0.0f) * (float)M##r.s6 * ys[c0 + 6]; \
    rowacc += fmaxf(v1[3] - thr, 0.0f) * (float)M##r.s7 * ys[c0 + 7]; \
    contrib += rowacc * xs[r0 + r]; }
  FOR16(FINP)
  #pragma unroll
  for (int m = 1; m < 64; m <<= 1) contrib += __shfl_xor(contrib, m, 64);
  if (lane == 0) wred[w] = contrib;
  __syncthreads();
  if (tid == 0) {
    float s2 = 0.0f;
    #pragma unroll
    for (int g = 0; g < 8; ++g) s2 += wred[g];
    gdist[blk] = s2;
  }
}

// ---------------- K5: deterministic finish: out = -mean_b(dist_b / m) ----------------
__global__ void k_final(const float* __restrict__ gdist, float* __restrict__ out) {
  int b = threadIdx.x & 63;
  float v = gdist[b] + gdist[b + 64] + gdist[b + 128] + gdist[b + 192];
  #pragma unroll
  for (int m = 1; m < 64; m <<= 1) v += __shfl_xor(v, m, 64);
  if (threadIdx.x == 0) out[0] = -v * (1.0f / (64.0f * 512.0f));
}

extern "C" void kernel_launch(void* const* d_in, const int* in_sizes, int n_in,
                              void* d_out, int out_size, void* d_ws, size_t ws_size,
                              hipStream_t stream) {
  const float* f1 = (const float*)d_in[0];
  const float* f2 = (const float*)d_in[1];
  char* ws = (char*)d_ws;
  __half* xn  = (__half*)(ws + 0);                 // 50,331,648 B
  __half* yn  = (__half*)(ws + 50331648);          // 50,331,648 B (dead after k_gemm)
  float* gpart = (float*)(ws + 50331648);          // 1 MB, overlaps yn (k_ipot only)
  float* cosm = (float*)(ws + 100663296);          // 67,108,864 B
  int*   meta = (int*)(ws + 167772160);            // 2 ints
  int*   cnt  = (int*)(ws + 167772160 + 256);      // 64 x 16 ints
  float* gdist = (float*)(ws + 167772160 + 256 + 4096);  // 256 floats

  k_init<<<1, 64, 0, stream>>>(meta, cnt);
  k_norm<<<16384, 256, 0, stream>>>(f1, f2, xn, yn);
  k_gemm<<<dim3(16, 64), 256, 0, stream>>>(xn, yn, cosm, meta);
  k_ipot<<<256, 512, 0, stream>>>(cosm, meta, cnt, gpart, gdist);
  k_final<<<1, 64, 0, stream>>>(gdist, (float*)d_out);
}

// Round 6
// 237.314 us; speedup vs baseline: 7.2253x; 2.1696x over previous
//
#include <hip/hip_runtime.h>
#include <hip/hip_fp16.h>

#define NN 512
#define DD 768

typedef _Float16 half8 __attribute__((ext_vector_type(8)));
typedef _Float16 half4 __attribute__((ext_vector_type(4)));
typedef _Float16 half2v __attribute__((ext_vector_type(2)));
typedef float f32x4 __attribute__((ext_vector_type(4)));

// order-preserving float<->int mapping (monotone for all floats incl. negatives)
__device__ __forceinline__ int f2ord(float f) {
  int i = __float_as_int(f);
  return i < 0 ? (i ^ 0x7fffffff) : i;
}
__device__ __forceinline__ float ord2f(int i) {
  return __int_as_float(i < 0 ? (i ^ 0x7fffffff) : i);
}

// ---------------- K0: init min/max meta + per-batch barrier counters ----------------
__global__ void k_init(int* meta, int* cnt) {
  int t = threadIdx.x;
  if (t == 0) {
    meta[0] = 0x7fffffff;  // ordered-int +max (min accumulator)
    meta[1] = 0x80000000;  // ordered-int -max (max accumulator)
  }
  if (t < 64) cnt[t * 16] = 0;  // 64B-strided per-batch counters
}

// ---------------- K1: row-normalize + fp16 cast ----------------
__global__ __launch_bounds__(256) void k_norm(const float* __restrict__ f1,
                                              const float* __restrict__ f2,
                                              __half* __restrict__ xn,
                                              __half* __restrict__ yn) {
  int row = blockIdx.x * 4 + (threadIdx.x >> 6);
  int lane = threadIdx.x & 63;
  int r = row & 32767;
  const float* src = (row < 32768 ? f1 : f2) + (size_t)r * DD;
  __half* dst = (row < 32768 ? xn : yn) + (size_t)r * DD;
  f32x4 v0 = *(const f32x4*)(src + lane * 4);
  f32x4 v1 = *(const f32x4*)(src + lane * 4 + 256);
  f32x4 v2 = *(const f32x4*)(src + lane * 4 + 512);
  float s = v0[0]*v0[0] + v0[1]*v0[1] + v0[2]*v0[2] + v0[3]*v0[3]
          + v1[0]*v1[0] + v1[1]*v1[1] + v1[2]*v1[2] + v1[3]*v1[3]
          + v2[0]*v2[0] + v2[1]*v2[1] + v2[2]*v2[2] + v2[3]*v2[3];
  #pragma unroll
  for (int m = 1; m < 64; m <<= 1) s += __shfl_xor(s, m, 64);
  float f = 1.0f / (sqrtf(s) + 1e-12f);
  union U { __half2 h2[2]; uint2 u; };
  U u0, u1, u2;
  u0.h2[0] = __floats2half2_rn(v0[0]*f, v0[1]*f); u0.h2[1] = __floats2half2_rn(v0[2]*f, v0[3]*f);
  u1.h2[0] = __floats2half2_rn(v1[0]*f, v1[1]*f); u1.h2[1] = __floats2half2_rn(v1[2]*f, v1[3]*f);
  u2.h2[0] = __floats2half2_rn(v2[0]*f, v2[1]*f); u2.h2[1] = __floats2half2_rn(v2[2]*f, v2[3]*f);
  *(uint2*)(dst + lane * 4)       = u0.u;
  *(uint2*)(dst + lane * 4 + 256) = u1.u;
  *(uint2*)(dst + lane * 4 + 512) = u2.u;
}

// ---------------- K2: batched fp16 MFMA GEMM: cos = 1 - xn @ yn^T ----------------
__global__ void k_gemm(const __half* __restrict__ xn, const __half* __restrict__ yn,
                       float* __restrict__ cosm, int* __restrict__ meta) {
  __shared__ __align__(16) __half As[4096];  // [128][32]
  __shared__ __align__(16) __half Bs[4096];
  __shared__ float rmin[4], rmax[4];
  const int b  = blockIdx.y;
  const int ti = blockIdx.x >> 2;
  const int tj = blockIdx.x & 3;
  const int tid = threadIdx.x;
  const int wv = tid >> 6, lane = tid & 63;
  const int wr = (wv >> 1) * 64, wc = (wv & 1) * 64;
  const __half* Ab = xn + ((size_t)b * NN + (size_t)ti * 128) * DD;
  const __half* Bb = yn + ((size_t)b * NN + (size_t)tj * 128) * DD;
  const int srow = tid >> 2;
  const int scol = (tid & 3) * 8;
  const __half* ga0 = Ab + (size_t)srow * DD + scol;
  const __half* ga1 = ga0 + (size_t)64 * DD;
  const __half* gb0 = Bb + (size_t)srow * DD + scol;
  const __half* gb1 = gb0 + (size_t)64 * DD;
  __half* la0 = As + tid * 8;
  __half* la1 = As + 2048 + tid * 8;
  __half* lb0 = Bs + tid * 8;
  __half* lb1 = Bs + 2048 + tid * 8;
  f32x4 acc[4][4] = {};
  const int fr = lane & 15;
  const int kb = (lane >> 4) * 8;
  typedef _Float16 mhalf8 __attribute__((ext_vector_type(8)));
  uint4 va0 = *(const uint4*)ga0;
  uint4 va1 = *(const uint4*)ga1;
  uint4 vb0 = *(const uint4*)gb0;
  uint4 vb1 = *(const uint4*)gb1;
  for (int kk = 0; kk < DD; kk += 32) {
    __syncthreads();
    *(uint4*)la0 = va0; *(uint4*)la1 = va1;
    *(uint4*)lb0 = vb0; *(uint4*)lb1 = vb1;
    __syncthreads();
    if (kk + 32 < DD) {
      va0 = *(const uint4*)(ga0 + kk + 32);
      va1 = *(const uint4*)(ga1 + kk + 32);
      vb0 = *(const uint4*)(gb0 + kk + 32);
      vb1 = *(const uint4*)(gb1 + kk + 32);
    }
    mhalf8 af[4], bf[4];
    #pragma unroll
    for (int g = 0; g < 4; ++g) {
      af[g] = *(const mhalf8*)(As + (wr + g * 16 + fr) * 32 + kb);
      bf[g] = *(const mhalf8*)(Bs + (wc + g * 16 + fr) * 32 + kb);
    }
    #pragma unroll
    for (int g = 0; g < 4; ++g) {
      #pragma unroll
      for (int h = 0; h < 4; ++h) {
        acc[g][h] = __builtin_amdgcn_mfma_f32_16x16x32_f16(af[g], bf[h], acc[g][h], 0, 0, 0);
      }
    }
  }
  float vmin = 1e30f, vmax = -1e30f;
  float* cb = cosm + (size_t)b * NN * NN;
  #pragma unroll
  for (int g = 0; g < 4; ++g) {
    #pragma unroll
    for (int h = 0; h < 4; ++h) {
      #pragma unroll
      for (int r2 = 0; r2 < 4; ++r2) {
        int row = ti * 128 + wr + g * 16 + (lane >> 4) * 4 + r2;
        int col = tj * 128 + wc + h * 16 + fr;
        float val = 1.0f - acc[g][h][r2];
        cb[(size_t)row * NN + col] = val;
        vmin = fminf(vmin, val); vmax = fmaxf(vmax, val);
      }
    }
  }
  #pragma unroll
  for (int m = 1; m < 64; m <<= 1) {
    vmin = fminf(vmin, __shfl_xor(vmin, m, 64));
    vmax = fmaxf(vmax, __shfl_xor(vmax, m, 64));
  }
  if (lane == 0) { rmin[wv] = vmin; rmax[wv] = vmax; }
  __syncthreads();
  if (tid == 0) {
    float bm = fminf(fminf(rmin[0], rmin[1]), fminf(rmin[2], rmin[3]));
    float bx = fmaxf(fmaxf(rmax[0], rmax[1]), fmaxf(rmax[2], rmax[3]));
    atomicMin(meta + 0, f2ord(bm));
    atomicMax(meta + 1, f2ord(bx));
  }
}

// ---------------- K3: 30 IPOT iterations, 4 blocks/batch, A/M in NAMED half8 registers ----
// blk -> batch b = blk&63, quarter qq = blk>>6 (partner blocks share an XCD under
// round-robin dispatch). Wave w owns 16 rows; lane owns 8 cols.
// FENCE-FREE cross-block exchange (round-4 fix: __threadfence + acq/rel atomics cost
// ~15 µs/iter in L2 writeback-invalidate on non-coherent XCD L2s):
//   - partials written with RELAXED AGENT atomic stores (bypass caches to coherent pt)
//   - __syncthreads() drains vmcnt -> stores complete before tid0 signals
//   - flag: RELAXED AGENT fetch_add; spin: RELAXED AGENT load (no buffer_inv)
//   - partner partials read with RELAXED AGENT atomic loads
#define FOR16(X) X(0) X(1) X(2) X(3) X(4) X(5) X(6) X(7) X(8) X(9) X(10) X(11) X(12) X(13) X(14) X(15)

__global__ __launch_bounds__(512, 2) void k_ipot(const float* __restrict__ cosm,
                                                 const int* __restrict__ meta,
                                                 int* __restrict__ cnt,
                                                 float* __restrict__ gpart,
                                                 float* __restrict__ gdist) {
  __shared__ float xs[128];
  __shared__ float ys[NN];
  __shared__ __align__(16) _Float16 zs[NN];
  __shared__ __align__(16) _Float16 csh[8][520];  // 8 waves x 512 cols (+8 pad)
  __shared__ float wred[8];
  const int blk = blockIdx.x;
  const int b = blk & 63, qq = blk >> 6;
  const int tid = threadIdx.x;
  const int w = tid >> 6, lane = tid & 63;
  const int r0 = w * 16;
  const int c0 = lane * 8;
  const float* cb = cosm + (size_t)b * NN * NN + (size_t)(qq * 128) * NN;
  const float gmn = ord2f(meta[0]);
  const float gmx = ord2f(meta[1]);
  const float thr = gmn + 0.1f * (gmx - gmn);

#define DECLAM(r) half8 A##r, M##r;
  FOR16(DECLAM)

#define INITAM(r) { \
    const float* rp = cb + (size_t)(r0 + r) * NN + c0; \
    f32x4 v0 = *(const f32x4*)rp; \
    f32x4 v1 = *(const f32x4*)(rp + 4); \
    A##r.s0 = (_Float16)__expf(-2.0f * fmaxf(v0[0] - thr, 0.0f)); \
    A##r.s1 = (_Float16)__expf(-2.0f * fmaxf(v0[1] - thr, 0.0f)); \
    A##r.s2 = (_Float16)__expf(-2.0f * fmaxf(v0[2] - thr, 0.0f)); \
    A##r.s3 = (_Float16)__expf(-2.0f * fmaxf(v0[3] - thr, 0.0f)); \
    A##r.s4 = (_Float16)__expf(-2.0f * fmaxf(v1[0] - thr, 0.0f)); \
    A##r.s5 = (_Float16)__expf(-2.0f * fmaxf(v1[1] - thr, 0.0f)); \
    A##r.s6 = (_Float16)__expf(-2.0f * fmaxf(v1[2] - thr, 0.0f)); \
    A##r.s7 = (_Float16)__expf(-2.0f * fmaxf(v1[3] - thr, 0.0f)); \
    M##r = A##r; }
  FOR16(INITAM)

  if (tid < 256) *(half2v*)(zs + 2 * tid) = (half2v){(_Float16)1.0f, (_Float16)1.0f};  // ẑ₁=1
  ys[tid] = 1.0f;  // ŷ₀=1 (512 threads cover 512 cols)
  __syncthreads();

  int* mycnt = cnt + b * 16;

  #pragma unroll 1
  for (int t = 1; t <= 30; ++t) {
    // ---- row pass: per-row partial = sum over own 8 cols of M*ẑ ----
    half8 zv = *(const half8*)(zs + c0);
    float rp16[16];
#define ROWP(r) { \
      half8 p = M##r * zv; \
      half4 q = p.lo + p.hi; \
      half2v q2 = q.lo + q.hi; \
      rp16[r] = (float)q2.x + (float)q2.y; }
    FOR16(ROWP)
    // reduce-scatter 16 row-partials over 64 lanes (static indices only)
    float c8[8];
    #pragma unroll
    for (int i = 0; i < 8; ++i) {
      float keep = (lane & 1) ? rp16[2*i+1] : rp16[2*i];
      float send = (lane & 1) ? rp16[2*i]   : rp16[2*i+1];
      c8[i] = keep + __shfl_xor(send, 1, 64);
    }
    float c4[4];
    #pragma unroll
    for (int i = 0; i < 4; ++i) {
      float keep = (lane & 2) ? c8[2*i+1] : c8[2*i];
      float send = (lane & 2) ? c8[2*i]   : c8[2*i+1];
      c4[i] = keep + __shfl_xor(send, 2, 64);
    }
    float d2[2];
    #pragma unroll
    for (int i = 0; i < 2; ++i) {
      float keep = (lane & 4) ? c4[2*i+1] : c4[2*i];
      float send = (lane & 4) ? c4[2*i]   : c4[2*i+1];
      d2[i] = keep + __shfl_xor(send, 4, 64);
    }
    float c1;
    {
      float keep = (lane & 8) ? d2[1] : d2[0];
      float send = (lane & 8) ? d2[0] : d2[1];
      c1 = keep + __shfl_xor(send, 8, 64);
    }
    c1 += __shfl_xor(c1, 16, 64);
    c1 += __shfl_xor(c1, 32, 64);
    if (lane < 16) xs[r0 + lane] = 1.0f / c1;  // x̂ for row (lane&15) of this wave
    __syncthreads();
    // ---- col pass: cac_j = sum over own 16 rows of M*x̂ ----
    half8 cac = (half8)(_Float16)0.0f;
#define COLP(r) { _Float16 xh = (_Float16)xs[r0 + r]; cac += M##r * xh; }
    FOR16(COLP)
    *(half8*)(&csh[w][c0]) = cac;
#define UPDM(r) M##r *= A##r;
    if (t < 30) { FOR16(UPDM) }  // M <- M∘A in regs, overlaps LDS latency
    __syncthreads();
    // ---- block-local col reduce -> RELAXED agent atomic stores (no fence) ----
    float* gp = gpart + ((size_t)((t & 1) * 256 + blk) * 512);
    if (tid < 256) {
      float a0 = 0.0f, a1 = 0.0f;
      #pragma unroll
      for (int g = 0; g < 8; ++g) {
        half2v pv = *(const half2v*)(&csh[g][2 * tid]);
        a0 += (float)pv.x; a1 += (float)pv.y;
      }
      __hip_atomic_store(gp + tid * 2,     a0, __ATOMIC_RELAXED, __HIP_MEMORY_SCOPE_AGENT);
      __hip_atomic_store(gp + tid * 2 + 1, a1, __ATOMIC_RELAXED, __HIP_MEMORY_SCOPE_AGENT);
    }
    __syncthreads();  // compiler emits s_waitcnt vmcnt(0) before s_barrier:
                      // every wave's atomic stores are complete at the coherent point
    // ---- 4-block barrier: monotonic counter, RELAXED only (no cache maintenance) ----
    if (tid == 0) {
      __hip_atomic_fetch_add(mycnt, 1, __ATOMIC_RELAXED, __HIP_MEMORY_SCOPE_AGENT);
      while (__hip_atomic_load(mycnt, __ATOMIC_RELAXED, __HIP_MEMORY_SCOPE_AGENT) < 4 * t)
        __builtin_amdgcn_s_sleep(1);
    }
    __syncthreads();
    // ---- read 4 partners' partials (blk = b + 64*q2), replicated ŷ/ẑ update ----
    if (tid < 256) {
      float a0 = 0.0f, a1 = 0.0f;
      #pragma unroll
      for (int q2 = 0; q2 < 4; ++q2) {
        const float* gpb = gpart + ((size_t)((t & 1) * 256 + b + 64 * q2) * 512);
        a0 += __hip_atomic_load(gpb + tid * 2,     __ATOMIC_RELAXED, __HIP_MEMORY_SCOPE_AGENT);
        a1 += __hip_atomic_load(gpb + tid * 2 + 1, __ATOMIC_RELAXED, __HIP_MEMORY_SCOPE_AGENT);
      }
      float yo0 = ys[2 * tid], yo1 = ys[2 * tid + 1];
      float y0 = 1.0f / a0;
      float y1 = 1.0f / a1;
      *(half2v*)(zs + 2 * tid) = (half2v){(_Float16)(y0 * y0 / yo0), (_Float16)(y1 * y1 / yo1)};
      ys[2 * tid] = y0; ys[2 * tid + 1] = y1;
    }
    __syncthreads();
  }

  // ---- dist partial = sum_ij relu(C-thr) * M_ij * x̂_i * ŷ_j over own patch ----
  float contrib = 0.0f;
#define FINP(r) { \
    const float* rp = cb + (size_t)(r0 + r) * NN + c0; \
    f32x4 v0 = *(const f32x4*)rp; \
    f32x4 v1 = *(const f32x4*)(rp + 4); \
    float rowacc = 0.0f; \
    rowacc += fmaxf(v0[0] - thr, 0.0f) * (float)M##r.s0 * ys[c0 + 0]; \
    rowacc += fmaxf(v0[1] - thr, 0.0f) * (float)M##r.s1 * ys[c0 + 1]; \
    rowacc += fmaxf(v0[2] - thr, 0.0f) * (float)M##r.s2 * ys[c0 + 2]; \
    rowacc += fmaxf(v0[3] - thr, 0.0f) * (float)M##r.s3 * ys[c0 + 3]; \
    rowacc += fmaxf(v1[0] - thr, 0.0f) * (float)M##r.s4 * ys[c0 + 4]; \
    rowacc += fmaxf(v1[1] - thr, 0.0f) * (float)M##r.s5 * ys[c0 + 5]; \
    rowacc += fmaxf(v1[2] - thr, 0.0f) * (float)M##r.s6 * ys[c0 + 6]; \
    rowacc += fmaxf(v1[3] - thr, 0.0f) * (float)M##r.s7 * ys[c0 + 7]; \
    contrib += rowacc * xs[r0 + r]; }
  FOR16(FINP)
  #pragma unroll
  for (int m = 1; m < 64; m <<= 1) contrib += __shfl_xor(contrib, m, 64);
  if (lane == 0) wred[w] = contrib;
  __syncthreads();
  if (tid == 0) {
    float s2 = 0.0f;
    #pragma unroll
    for (int g = 0; g < 8; ++g) s2 += wred[g];
    gdist[blk] = s2;
  }
}

// ---------------- K5: deterministic finish: out = -mean_b(dist_b / m) ----------------
__global__ void k_final(const float* __restrict__ gdist, float* __restrict__ out) {
  int b = threadIdx.x & 63;
  float v = gdist[b] + gdist[b + 64] + gdist[b + 128] + gdist[b + 192];
  #pragma unroll
  for (int m = 1; m < 64; m <<= 1) v += __shfl_xor(v, m, 64);
  if (threadIdx.x == 0) out[0] = -v * (1.0f / (64.0f * 512.0f));
}

extern "C" void kernel_launch(void* const* d_in, const int* in_sizes, int n_in,
                              void* d_out, int out_size, void* d_ws, size_t ws_size,
                              hipStream_t stream) {
  const float* f1 = (const float*)d_in[0];
  const float* f2 = (const float*)d_in[1];
  char* ws = (char*)d_ws;
  __half* xn  = (__half*)(ws + 0);                 // 50,331,648 B
  __half* yn  = (__half*)(ws + 50331648);          // 50,331,648 B (dead after k_gemm)
  float* gpart = (float*)(ws + 50331648);          // 1 MB, overlaps yn (k_ipot only)
  float* cosm = (float*)(ws + 100663296);          // 67,108,864 B
  int*   meta = (int*)(ws + 167772160);            // 2 ints
  int*   cnt  = (int*)(ws + 167772160 + 256);      // 64 x 16 ints
  float* gdist = (float*)(ws + 167772160 + 256 + 4096);  // 256 floats

  k_init<<<1, 64, 0, stream>>>(meta, cnt);
  k_norm<<<16384, 256, 0, stream>>>(f1, f2, xn, yn);
  k_gemm<<<dim3(16, 64), 256, 0, stream>>>(xn, yn, cosm, meta);
  k_ipot<<<256, 512, 0, stream>>>(cosm, meta, cnt, gpart, gdist);
  k_final<<<1, 64, 0, stream>>>(gdist, (float*)d_out);
}